// Round 1
// baseline (436.549 us; speedup 1.0000x reference)
//
#include <hip/hip_runtime.h>
#include <hip/hip_bf16.h>

#define NN 8192
#define INDIM 256
#define HID 64
#define COLS 128   // HEADS*HID

typedef __bf16 bf16x8 __attribute__((ext_vector_type(8)));
typedef float  f32x4  __attribute__((ext_vector_type(4)));

// ---- workspace layout (bytes) ----
#define WS_FEATB 0x000000u  // bf16 [256][128][32]  = 2 MB   (B-frag packed feat)
#define WS_S2    0x200000u  // f32 [2][8192]
#define WS_N2    0x210000u  // f32 [2][8192]
#define WS_WPK   0x220000u  // bf16 [8][128][32]    = 64 KB  (B-frag packed W)
#define WS_DEN   0x230000u  // f32 [2][8192]
#define WS_NUM   0x240000u  // f32 [8192][128]      = 4 MB
#define WS_END   0x640000u

// Zero den+num (harness poisons ws with 0xAA each call).
__global__ void zero_kernel(float4* __restrict__ p) {
    p[blockIdx.x * 256 + threadIdx.x] = float4{0.f, 0.f, 0.f, 0.f};
}

// Pack W [2][256][64] f32 -> wpk[(k/32)*128 + col][32] bf16, col = h*64+c.
__global__ void pack_w(const float* __restrict__ W, __bf16* __restrict__ wpk) {
    int idx = blockIdx.x * 256 + threadIdx.x;       // 0..32767
    int h = idx >> 14, k = (idx >> 6) & 255, c = idx & 63;
    int col = h * 64 + c;
    wpk[((k >> 5) * 128 + col) * 32 + (k & 31)] = (__bf16)W[idx];
}

// feat = X @ W (bf16 MFMA), plus s = feat@a_self, n = feat@a_neigh per head,
// and feat stored in B-fragment-packed bf16 layout for the main kernel.
// 1 wave per block, 16 rows per block.
__global__ __launch_bounds__(64) void feat_kernel(
        const float* __restrict__ X, const float* __restrict__ a_self,
        const float* __restrict__ a_neigh, const __bf16* __restrict__ wpk,
        __bf16* __restrict__ featB, float* __restrict__ s2, float* __restrict__ n2) {
    const int l = threadIdx.x;
    const int lane16 = l & 15, kg = l >> 4;
    const int rbase = blockIdx.x * 16;
    const int arow = rbase + lane16;

    f32x4 acc[8] = {};
    const float* xrow = X + (size_t)arow * INDIM + kg * 8;
#pragma unroll
    for (int ks = 0; ks < 8; ++ks) {
        float4 x0 = *(const float4*)(xrow + ks * 32);
        float4 x1 = *(const float4*)(xrow + ks * 32 + 4);
        bf16x8 afrag;
        afrag[0] = (__bf16)x0.x; afrag[1] = (__bf16)x0.y;
        afrag[2] = (__bf16)x0.z; afrag[3] = (__bf16)x0.w;
        afrag[4] = (__bf16)x1.x; afrag[5] = (__bf16)x1.y;
        afrag[6] = (__bf16)x1.z; afrag[7] = (__bf16)x1.w;
        const __bf16* wp = wpk + (ks * 128 + lane16) * 32 + kg * 8;
#pragma unroll
        for (int t = 0; t < 8; ++t) {
            bf16x8 bfrag = *(const bf16x8*)(wp + t * 512);   // t*16 cols * 32
            acc[t] = __builtin_amdgcn_mfma_f32_16x16x32_bf16(afrag, bfrag, acc[t], 0, 0, 0);
        }
    }

    // C layout: col = t*16 + lane16, row = rbase + kg*4 + r
    const int crow0 = rbase + kg * 4;
    float ps[2][4] = {}, pn[2][4] = {};
#pragma unroll
    for (int t = 0; t < 8; ++t) {
        int col = t * 16 + lane16;
        int h = col >> 6, c = col & 63;
        float as = a_self[h * 64 + c];
        float an = a_neigh[h * 64 + c];
#pragma unroll
        for (int r = 0; r < 4; ++r) {
            float fv = acc[t][r];
            int j = crow0 + r;
            featB[((j >> 5) * 128 + col) * 32 + (j & 31)] = (__bf16)fv;
            ps[h][r] += fv * as;
            pn[h][r] += fv * an;
        }
    }
    // reduce across the 16 lanes (cols) of each row
#pragma unroll
    for (int h = 0; h < 2; ++h) {
#pragma unroll
        for (int r = 0; r < 4; ++r) {
            float v1 = ps[h][r], v2 = pn[h][r];
#pragma unroll
            for (int m = 1; m <= 8; m <<= 1) {
                v1 += __shfl_xor(v1, m);
                v2 += __shfl_xor(v2, m);
            }
            if (lane16 == 0) {
                s2[h * NN + crow0 + r] = v1;
                n2[h * NN + crow0 + r] = v2;
            }
        }
    }
}

// Main fused kernel: per wave 16 rows x 128 cols, K-chunk of 1024.
// dense_ij = exp(exp(-(s_i-n_j)^2)) * A_ij computed in-register, fed to MFMA.
__global__ __launch_bounds__(256, 4) void attn_kernel(
        const float* __restrict__ A, const float* __restrict__ s2g,
        const float* __restrict__ n2g, const __bf16* __restrict__ featB,
        float* __restrict__ num, float* __restrict__ den) {
    __shared__ float lds_n[2 * 1024];
    const int tid = threadIdx.x, l = tid & 63, wave = tid >> 6;
    const int lane16 = l & 15, kg = l >> 4;
    const int j0 = blockIdx.x * 1024;
    const int rbase = blockIdx.y * 64 + wave * 16;
    const int row = rbase + lane16;

    for (int idx = tid; idx < 2048; idx += 256) {
        int h = idx >> 10, jj = idx & 1023;
        lds_n[idx] = n2g[h * NN + j0 + jj];
    }
    __syncthreads();

    const float ss0 = s2g[row];
    const float ss1 = s2g[NN + row];
    f32x4 acc[8] = {};          // [h*4 + t]
    float den0 = 0.f, den1 = 0.f;

    const float* arow_p = A + (size_t)row * NN + j0 + kg * 8;
    const int kb0 = j0 >> 5;

    for (int kb = 0; kb < 32; ++kb) {
        float4 a0 = *(const float4*)(arow_p + kb * 32);
        float4 a1 = *(const float4*)(arow_p + kb * 32 + 4);
        float av[8] = {a0.x, a0.y, a0.z, a0.w, a1.x, a1.y, a1.z, a1.w};

        const float* np0 = &lds_n[kb * 32 + kg * 8];
        float4 n0a = *(const float4*)(np0);
        float4 n0b = *(const float4*)(np0 + 4);
        float4 n1a = *(const float4*)(np0 + 1024);
        float4 n1b = *(const float4*)(np0 + 1028);
        float nv0[8] = {n0a.x, n0a.y, n0a.z, n0a.w, n0b.x, n0b.y, n0b.z, n0b.w};
        float nv1[8] = {n1a.x, n1a.y, n1a.z, n1a.w, n1b.x, n1b.y, n1b.z, n1b.w};

        bf16x8 fa0, fa1;
#pragma unroll
        for (int r = 0; r < 8; ++r) {
            float d0 = ss0 - nv0[r];
            float d1 = ss1 - nv1[r];
            float w0 = __expf(__expf(-d0 * d0));
            float w1 = __expf(__expf(-d1 * d1));
            float v0 = av[r] * w0;
            float v1 = av[r] * w1;
            den0 += v0; den1 += v1;
            fa0[r] = (__bf16)v0;
            fa1[r] = (__bf16)v1;
        }

        const __bf16* fb = featB + (size_t)(kb0 + kb) * 4096 + kg * 8;
#pragma unroll
        for (int t = 0; t < 4; ++t) {
            bf16x8 b0 = *(const bf16x8*)(fb + (t * 16 + lane16) * 32);
            acc[t] = __builtin_amdgcn_mfma_f32_16x16x32_bf16(fa0, b0, acc[t], 0, 0, 0);
        }
#pragma unroll
        for (int t = 0; t < 4; ++t) {
            bf16x8 b1 = *(const bf16x8*)(fb + (64 + t * 16 + lane16) * 32);
            acc[4 + t] = __builtin_amdgcn_mfma_f32_16x16x32_bf16(fa1, b1, acc[4 + t], 0, 0, 0);
        }
    }

    // row-sum (denominator) reduce across the 4 k-groups
    den0 += __shfl_xor(den0, 16); den0 += __shfl_xor(den0, 32);
    den1 += __shfl_xor(den1, 16); den1 += __shfl_xor(den1, 32);
    if (l < 16) {
        atomicAdd(&den[row], den0);
        atomicAdd(&den[NN + row], den1);
    }

    // numerator partials
    const int crow = rbase + kg * 4;
#pragma unroll
    for (int ht = 0; ht < 8; ++ht) {
        int col = (ht >> 2) * 64 + (ht & 3) * 16 + lane16;
#pragma unroll
        for (int r = 0; r < 4; ++r)
            atomicAdd(&num[(size_t)(crow + r) * COLS + col], acc[ht][r]);
    }
}

// out = relu(num/den + b)
__global__ void finalize_kernel(const float* __restrict__ num, const float* __restrict__ den,
                                const float* __restrict__ b, float* __restrict__ out) {
    int gid = blockIdx.x * 256 + threadIdx.x;   // one float4 each
    int idx = gid * 4;
    int row = idx >> 7, col = idx & 127;
    float dv = den[(col >> 6) * NN + row];
    float inv = 1.f / dv;
    float4 nv = *(const float4*)(num + idx);
    float4 bv = *(const float4*)(b + col);
    float4 o;
    o.x = fmaxf(nv.x * inv + bv.x, 0.f);
    o.y = fmaxf(nv.y * inv + bv.y, 0.f);
    o.z = fmaxf(nv.z * inv + bv.z, 0.f);
    o.w = fmaxf(nv.w * inv + bv.w, 0.f);
    *(float4*)(out + idx) = o;
}

extern "C" void kernel_launch(void* const* d_in, const int* in_sizes, int n_in,
                              void* d_out, int out_size, void* d_ws, size_t ws_size,
                              hipStream_t stream) {
    const float* X       = (const float*)d_in[0];
    const float* A       = (const float*)d_in[1];
    const float* W       = (const float*)d_in[2];
    const float* b       = (const float*)d_in[3];
    const float* a_self  = (const float*)d_in[4];
    const float* a_neigh = (const float*)d_in[5];
    float* out = (float*)d_out;
    char* ws = (char*)d_ws;

    __bf16* featB = (__bf16*)(ws + WS_FEATB);
    float*  s2    = (float*)(ws + WS_S2);
    float*  n2    = (float*)(ws + WS_N2);
    __bf16* wpk   = (__bf16*)(ws + WS_WPK);
    float*  den   = (float*)(ws + WS_DEN);
    float*  num   = (float*)(ws + WS_NUM);

    // den (64KB) + num (4MB) are contiguous: 0x410000 bytes = 266240 float4
    hipLaunchKernelGGL(zero_kernel, dim3(1040), dim3(256), 0, stream, (float4*)(ws + WS_DEN));
    hipLaunchKernelGGL(pack_w, dim3(128), dim3(256), 0, stream, W, wpk);
    hipLaunchKernelGGL(feat_kernel, dim3(512), dim3(64), 0, stream,
                       X, a_self, a_neigh, wpk, featB, s2, n2);
    hipLaunchKernelGGL(attn_kernel, dim3(8, 128), dim3(256), 0, stream,
                       A, s2, n2, featB, num, den);
    hipLaunchKernelGGL(finalize_kernel, dim3(1024), dim3(256), 0, stream,
                       num, den, b, out);
}

// Round 2
// 422.598 us; speedup vs baseline: 1.0330x; 1.0330x over previous
//
#include <hip/hip_runtime.h>
#include <hip/hip_bf16.h>

#define NN 8192
#define INDIM 256
#define HID 64
#define COLS 128   // HEADS*HID

typedef __bf16 bf16x8 __attribute__((ext_vector_type(8)));
typedef float  f32x4  __attribute__((ext_vector_type(4)));

// ---- workspace layout (bytes) ----
#define WS_FEATB 0x000000u  // bf16 [256][128][32]  = 2 MB   (B-frag packed feat)
#define WS_S2    0x200000u  // f32 [2][8192]
#define WS_N2    0x210000u  // f32 [2][8192]
#define WS_WPK   0x220000u  // bf16 [8][128][32]    = 64 KB  (B-frag packed W)
#define WS_DEN   0x230000u  // f32 [2][8192]
#define WS_NUM   0x240000u  // f32 [8192][128]      = 4 MB
#define WS_END   0x640000u

// Zero den+num (harness poisons ws with 0xAA each call).
__global__ void zero_kernel(float4* __restrict__ p) {
    p[blockIdx.x * 256 + threadIdx.x] = float4{0.f, 0.f, 0.f, 0.f};
}

// Pack W [2][256][64] f32 -> wpk[(k/32)*128 + col][32] bf16, col = h*64+c.
__global__ void pack_w(const float* __restrict__ W, __bf16* __restrict__ wpk) {
    int idx = blockIdx.x * 256 + threadIdx.x;       // 0..32767
    int h = idx >> 14, k = (idx >> 6) & 255, c = idx & 63;
    int col = h * 64 + c;
    wpk[((k >> 5) * 128 + col) * 32 + (k & 31)] = (__bf16)W[idx];
}

// feat = X @ W (bf16 MFMA), plus s = feat@a_self, n = feat@a_neigh per head,
// and feat stored in B-fragment-packed bf16 layout for the main kernel.
__global__ __launch_bounds__(64) void feat_kernel(
        const float* __restrict__ X, const float* __restrict__ a_self,
        const float* __restrict__ a_neigh, const __bf16* __restrict__ wpk,
        __bf16* __restrict__ featB, float* __restrict__ s2, float* __restrict__ n2) {
    const int l = threadIdx.x;
    const int lane16 = l & 15, kg = l >> 4;
    const int rbase = blockIdx.x * 16;
    const int arow = rbase + lane16;

    f32x4 acc[8] = {};
    const float* xrow = X + (size_t)arow * INDIM + kg * 8;
#pragma unroll
    for (int ks = 0; ks < 8; ++ks) {
        float4 x0 = *(const float4*)(xrow + ks * 32);
        float4 x1 = *(const float4*)(xrow + ks * 32 + 4);
        bf16x8 afrag;
        afrag[0] = (__bf16)x0.x; afrag[1] = (__bf16)x0.y;
        afrag[2] = (__bf16)x0.z; afrag[3] = (__bf16)x0.w;
        afrag[4] = (__bf16)x1.x; afrag[5] = (__bf16)x1.y;
        afrag[6] = (__bf16)x1.z; afrag[7] = (__bf16)x1.w;
        const __bf16* wp = wpk + (ks * 128 + lane16) * 32 + kg * 8;
#pragma unroll
        for (int t = 0; t < 8; ++t) {
            bf16x8 bfrag = *(const bf16x8*)(wp + t * 512);
            acc[t] = __builtin_amdgcn_mfma_f32_16x16x32_bf16(afrag, bfrag, acc[t], 0, 0, 0);
        }
    }

    const int crow0 = rbase + kg * 4;
    float ps[2][4] = {}, pn[2][4] = {};
#pragma unroll
    for (int t = 0; t < 8; ++t) {
        int col = t * 16 + lane16;
        int h = col >> 6, c = col & 63;
        float as = a_self[h * 64 + c];
        float an = a_neigh[h * 64 + c];
#pragma unroll
        for (int r = 0; r < 4; ++r) {
            float fv = acc[t][r];
            int j = crow0 + r;
            featB[((j >> 5) * 128 + col) * 32 + (j & 31)] = (__bf16)fv;
            ps[h][r] += fv * as;
            pn[h][r] += fv * an;
        }
    }
#pragma unroll
    for (int h = 0; h < 2; ++h) {
#pragma unroll
        for (int r = 0; r < 4; ++r) {
            float v1 = ps[h][r], v2 = pn[h][r];
#pragma unroll
            for (int m = 1; m <= 8; m <<= 1) {
                v1 += __shfl_xor(v1, m);
                v2 += __shfl_xor(v2, m);
            }
            if (lane16 == 0) {
                s2[h * NN + crow0 + r] = v1;
                n2[h * NN + crow0 + r] = v2;
            }
        }
    }
}

// Main fused kernel: per wave 16 rows x 128 cols, K-chunk of 1024.
// k-loop start phase rotated per y-block to spread concurrent A reads
// across all HBM channels (32 KB row stride aliases channels otherwise).
__global__ __launch_bounds__(256, 4) void attn_kernel(
        const float* __restrict__ A, const float* __restrict__ s2g,
        const float* __restrict__ n2g, const __bf16* __restrict__ featB,
        float* __restrict__ num, float* __restrict__ den) {
    __shared__ float lds_n[2 * 1024];
    const int tid = threadIdx.x, l = tid & 63, wave = tid >> 6;
    const int lane16 = l & 15, kg = l >> 4;
    const int j0 = blockIdx.x * 1024;
    const int rbase = blockIdx.y * 64 + wave * 16;
    const int row = rbase + lane16;

    for (int idx = tid; idx < 2048; idx += 256) {
        int h = idx >> 10, jj = idx & 1023;
        lds_n[idx] = n2g[h * NN + j0 + jj];
    }
    __syncthreads();

    const float ss0 = s2g[row];
    const float ss1 = s2g[NN + row];
    f32x4 acc[8] = {};          // [h*4 + t]
    float den0 = 0.f, den1 = 0.f;

    const float* arow_p = A + (size_t)row * NN + j0 + kg * 8;
    const int kb0 = j0 >> 5;

    int kb = (blockIdx.y * 5) & 31;     // rotated start phase
    float4 a0 = *(const float4*)(arow_p + kb * 32);
    float4 a1 = *(const float4*)(arow_p + kb * 32 + 4);

    for (int i = 0; i < 32; ++i) {
        const int kbn = (kb + 1) & 31;
        float4 p0 = a0, p1 = a1;
        if (i < 31) {                   // register double-buffer prefetch
            a0 = *(const float4*)(arow_p + kbn * 32);
            a1 = *(const float4*)(arow_p + kbn * 32 + 4);
        }
        float av[8] = {p0.x, p0.y, p0.z, p0.w, p1.x, p1.y, p1.z, p1.w};

        const float* np0 = &lds_n[kb * 32 + kg * 8];
        float4 n0a = *(const float4*)(np0);
        float4 n0b = *(const float4*)(np0 + 4);
        float4 n1a = *(const float4*)(np0 + 1024);
        float4 n1b = *(const float4*)(np0 + 1028);
        float nv0[8] = {n0a.x, n0a.y, n0a.z, n0a.w, n0b.x, n0b.y, n0b.z, n0b.w};
        float nv1[8] = {n1a.x, n1a.y, n1a.z, n1a.w, n1b.x, n1b.y, n1b.z, n1b.w};

        bf16x8 fa0, fa1;
#pragma unroll
        for (int r = 0; r < 8; ++r) {
            float d0 = ss0 - nv0[r];
            float d1 = ss1 - nv1[r];
            float w0 = __expf(__expf(-d0 * d0));
            float w1 = __expf(__expf(-d1 * d1));
            float v0 = av[r] * w0;
            float v1 = av[r] * w1;
            den0 += v0; den1 += v1;
            fa0[r] = (__bf16)v0;
            fa1[r] = (__bf16)v1;
        }

        const __bf16* fb = featB + (size_t)(kb0 + kb) * 4096 + kg * 8;
#pragma unroll
        for (int t = 0; t < 4; ++t) {
            bf16x8 b0 = *(const bf16x8*)(fb + (t * 16 + lane16) * 32);
            acc[t] = __builtin_amdgcn_mfma_f32_16x16x32_bf16(fa0, b0, acc[t], 0, 0, 0);
        }
#pragma unroll
        for (int t = 0; t < 4; ++t) {
            bf16x8 b1 = *(const bf16x8*)(fb + (64 + t * 16 + lane16) * 32);
            acc[4 + t] = __builtin_amdgcn_mfma_f32_16x16x32_bf16(fa1, b1, acc[4 + t], 0, 0, 0);
        }
        kb = kbn;
    }

    den0 += __shfl_xor(den0, 16); den0 += __shfl_xor(den0, 32);
    den1 += __shfl_xor(den1, 16); den1 += __shfl_xor(den1, 32);
    if (l < 16) {
        atomicAdd(&den[row], den0);
        atomicAdd(&den[NN + row], den1);
    }

    const int crow = rbase + kg * 4;
#pragma unroll
    for (int ht = 0; ht < 8; ++ht) {
        int col = (ht >> 2) * 64 + (ht & 3) * 16 + lane16;
#pragma unroll
        for (int r = 0; r < 4; ++r)
            atomicAdd(&num[(size_t)(crow + r) * COLS + col], acc[ht][r]);
    }
}

// out = relu(num/den + b)
__global__ void finalize_kernel(const float* __restrict__ num, const float* __restrict__ den,
                                const float* __restrict__ b, float* __restrict__ out) {
    int gid = blockIdx.x * 256 + threadIdx.x;   // one float4 each
    int idx = gid * 4;
    int row = idx >> 7, col = idx & 127;
    float dv = den[(col >> 6) * NN + row];
    float inv = 1.f / dv;
    float4 nv = *(const float4*)(num + idx);
    float4 bv = *(const float4*)(b + col);
    float4 o;
    o.x = fmaxf(nv.x * inv + bv.x, 0.f);
    o.y = fmaxf(nv.y * inv + bv.y, 0.f);
    o.z = fmaxf(nv.z * inv + bv.z, 0.f);
    o.w = fmaxf(nv.w * inv + bv.w, 0.f);
    *(float4*)(out + idx) = o;
}

extern "C" void kernel_launch(void* const* d_in, const int* in_sizes, int n_in,
                              void* d_out, int out_size, void* d_ws, size_t ws_size,
                              hipStream_t stream) {
    const float* X       = (const float*)d_in[0];
    const float* A       = (const float*)d_in[1];
    const float* W       = (const float*)d_in[2];
    const float* b       = (const float*)d_in[3];
    const float* a_self  = (const float*)d_in[4];
    const float* a_neigh = (const float*)d_in[5];
    float* out = (float*)d_out;
    char* ws = (char*)d_ws;

    __bf16* featB = (__bf16*)(ws + WS_FEATB);
    float*  s2    = (float*)(ws + WS_S2);
    float*  n2    = (float*)(ws + WS_N2);
    __bf16* wpk   = (__bf16*)(ws + WS_WPK);
    float*  den   = (float*)(ws + WS_DEN);
    float*  num   = (float*)(ws + WS_NUM);

    hipLaunchKernelGGL(zero_kernel, dim3(1040), dim3(256), 0, stream, (float4*)(ws + WS_DEN));
    hipLaunchKernelGGL(pack_w, dim3(128), dim3(256), 0, stream, W, wpk);
    hipLaunchKernelGGL(feat_kernel, dim3(512), dim3(64), 0, stream,
                       X, a_self, a_neigh, wpk, featB, s2, n2);
    hipLaunchKernelGGL(attn_kernel, dim3(8, 128), dim3(256), 0, stream,
                       A, s2, n2, featB, num, den);
    hipLaunchKernelGGL(finalize_kernel, dim3(1024), dim3(256), 0, stream,
                       num, den, b, out);
}